// Round 5
// baseline (316.091 us; speedup 1.0000x reference)
//
#include <hip/hip_runtime.h>

#define N_NODES 100000
#define N_EDGES 3200000
#define F_IN 128
#define HID 16

#define SHIFT 8
#define NPB 256                                 // nodes per bucket
#define NB ((N_NODES + NPB - 1) / NPB)          // 391 buckets
#define CHUNK 2048
#define NCHUNK ((N_EDGES + CHUNK - 1) / CHUNK)  // 1563 chunks
#define MAXBE 12288                             // max edges per bucket (mean 8184, +45 sigma)
#define CPAD 16                                 // cursor stride (one 64B line per bucket)

// ---------------- bucket histogram ----------------
__global__ __launch_bounds__(256) void k_hist(const int* __restrict__ dst,
                                              int* __restrict__ gcount, int E) {
    __shared__ int cnt[NB];
    for (int b = threadIdx.x; b < NB; b += 256) cnt[b] = 0;
    __syncthreads();
    for (int e = blockIdx.x * 256 + threadIdx.x; e < E; e += gridDim.x * 256)
        atomicAdd(&cnt[dst[e] >> SHIFT], 1);
    __syncthreads();
    for (int b = threadIdx.x; b < NB; b += 256)
        if (cnt[b]) atomicAdd(&gcount[b * CPAD], cnt[b]);
}

// ---------------- scan buckets (1 block) ----------------
__global__ __launch_bounds__(512) void k_scan(const int* __restrict__ gcount,
                                              int* __restrict__ bbase,
                                              int* __restrict__ bcursor, int E) {
    __shared__ int s[512];
    int t = threadIdx.x;
    int v = (t < NB) ? gcount[t * CPAD] : 0;
    s[t] = v;
    __syncthreads();
#pragma unroll
    for (int o = 1; o < 512; o <<= 1) {
        int x = (t >= o) ? s[t - o] : 0;
        __syncthreads();
        s[t] += x;
        __syncthreads();
    }
    if (t < NB) {
        int ex = s[t] - v;
        bbase[t] = ex;
        bcursor[t * CPAD] = ex;
    }
    if (t == 0) bbase[NB] = E;
}

// ---------------- partition edges into buckets (packed src<<8|dstLocal) ----------------
__global__ __launch_bounds__(256) void k_part(const int* __restrict__ src,
                                              const int* __restrict__ dst,
                                              int* __restrict__ bcursor,
                                              unsigned* __restrict__ ebuf, int E) {
    __shared__ int lcnt[NB];
    __shared__ int lcur[NB];
    int t = threadIdx.x;
    for (int b = t; b < NB; b += 256) lcnt[b] = 0;
    __syncthreads();
    int e0 = blockIdx.x * CHUNK;
    int e1 = min(e0 + CHUNK, E);
    for (int e = e0 + t; e < e1; e += 256) atomicAdd(&lcnt[dst[e] >> SHIFT], 1);
    __syncthreads();
    for (int b = t; b < NB; b += 256) {
        int c = lcnt[b];
        lcur[b] = c ? atomicAdd(&bcursor[b * CPAD], c) : 0;
    }
    __syncthreads();
    for (int e = e0 + t; e < e1; e += 256) {
        int d = dst[e];
        int b = d >> SHIFT;
        int p = atomicAdd(&lcur[b], 1);
        ebuf[p] = ((unsigned)src[e] << SHIFT) | (unsigned)(d & (NPB - 1));
    }
}

// ---------------- per-bucket LDS counting-sort -> exact CSR (+dinv) ----------------
__global__ __launch_bounds__(256) void k_sort(const unsigned* __restrict__ ebuf,
                                              const int* __restrict__ bbase,
                                              int* __restrict__ off,
                                              int* __restrict__ ebuf2,
                                              float* __restrict__ dinv, int N, int E) {
    __shared__ int hist[NPB];
    __shared__ int sc[NPB];
    __shared__ int cur[NPB];
    __shared__ int sbuf[MAXBE];  // 48 KB
    int t = threadIdx.x;
    int b = blockIdx.x;
    int e0 = bbase[b], e1 = bbase[b + 1];
    int ne = e1 - e0;
    hist[t] = 0;
    __syncthreads();
    for (int e = t; e < ne; e += 256) atomicAdd(&hist[ebuf[e0 + e] & (NPB - 1)], 1);
    __syncthreads();
    int v = hist[t];
    sc[t] = v;
    __syncthreads();
#pragma unroll
    for (int o = 1; o < 256; o <<= 1) {
        int x = (t >= o) ? sc[t - o] : 0;
        __syncthreads();
        sc[t] += x;
        __syncthreads();
    }
    int ex = sc[t] - v;  // exclusive prefix within bucket
    cur[t] = ex;
    int i = (b << SHIFT) + t;
    if (i < N) {
        off[i] = e0 + ex;
        dinv[i] = rsqrtf((float)(v + 1));  // +1 self-loop
    }
    if (b == NB - 1 && t == 0) off[N] = E;
    __syncthreads();
    for (int e = t; e < ne; e += 256) {
        unsigned u = ebuf[e0 + e];
        int p = atomicAdd(&cur[u & (NPB - 1)], 1);
        sbuf[p] = (int)(u >> SHIFT);
    }
    __syncthreads();
    for (int e = t; e < ne; e += 256) ebuf2[e0 + e] = sbuf[e];  // coalesced
}

// ---------------- GEMM1: g = (x @ W1) * dinv,  K=128, lane-pair per row ----------------
__global__ __launch_bounds__(256) void k_gemm1(const float* __restrict__ x,
                                               const float* __restrict__ W1,
                                               const float* __restrict__ dinv,
                                               float* __restrict__ g, int N) {
    __shared__ float w[F_IN * HID];
    for (int t = threadIdx.x; t < F_IN * HID; t += 256) w[t] = W1[t];
    __syncthreads();
    int t = threadIdx.x;
    int half = t & 1;
    int i = blockIdx.x * 128 + (t >> 1);
    float acc[HID];
#pragma unroll
    for (int n = 0; n < HID; n++) acc[n] = 0.f;
    if (i < N) {
        const float4* xr = (const float4*)(x + (size_t)i * F_IN + half * (F_IN / 2));
#pragma unroll 4
        for (int k4 = 0; k4 < F_IN / 8; k4++) {  // 16 iters, 64 features per lane
            float4 xv = xr[k4];
            int k = half * (F_IN / 2) + k4 * 4;
#pragma unroll
            for (int n = 0; n < HID; n++) {
                acc[n] += xv.x * w[(k + 0) * HID + n] + xv.y * w[(k + 1) * HID + n] +
                          xv.z * w[(k + 2) * HID + n] + xv.w * w[(k + 3) * HID + n];
            }
        }
    }
#pragma unroll
    for (int n = 0; n < HID; n++) acc[n] += __shfl_xor(acc[n], 1);
    if (half == 0 && i < N) {
        float dv = dinv[i];
        float4* go = (float4*)(g + (size_t)i * HID);
#pragma unroll
        for (int n4 = 0; n4 < 4; n4++) {
            float4 o;
            o.x = acc[n4 * 4 + 0] * dv;
            o.y = acc[n4 * 4 + 1] * dv;
            o.z = acc[n4 * 4 + 2] * dv;
            o.w = acc[n4 * 4 + 3] * dv;
            go[n4] = o;
        }
    }
}

// ---------------- gather-sum + finish: wave per node ----------------
// 64 lanes = 16 edges x 4 float4-slices per iteration, shfl_xor tree reduce.
__global__ __launch_bounds__(256) void k_gather(const float* __restrict__ g,
                                                const int* __restrict__ off,
                                                const int* __restrict__ ebuf,
                                                const float* __restrict__ dinv,
                                                const float* __restrict__ bias,
                                                float* __restrict__ h, int N, int do_relu) {
    int i = (blockIdx.x * 256 + threadIdx.x) >> 6;  // node = global wave id
    int lane = threadIdx.x & 63;
    if (i >= N) return;
    int e0 = off[i], e1 = off[i + 1];
    int j = lane & 3;
    float4 a = make_float4(0.f, 0.f, 0.f, 0.f);
    for (int e = e0 + (lane >> 2); e < e1; e += 16) {
        int s = ebuf[e];
        float4 v = ((const float4*)(g + (size_t)s * HID))[j];
        a.x += v.x;
        a.y += v.y;
        a.z += v.z;
        a.w += v.w;
    }
#pragma unroll
    for (int m = 4; m <= 32; m <<= 1) {
        a.x += __shfl_xor(a.x, m);
        a.y += __shfl_xor(a.y, m);
        a.z += __shfl_xor(a.z, m);
        a.w += __shfl_xor(a.w, m);
    }
    if (lane < 4) {
        float4 self = ((const float4*)(g + (size_t)i * HID))[j];
        float4 bb = ((const float4*)bias)[j];
        float dv = dinv[i];
        float4 o;
        o.x = dv * (a.x + self.x) + bb.x;
        o.y = dv * (a.y + self.y) + bb.y;
        o.z = dv * (a.z + self.z) + bb.z;
        o.w = dv * (a.w + self.w) + bb.w;
        if (do_relu) {
            o.x = fmaxf(o.x, 0.f);
            o.y = fmaxf(o.y, 0.f);
            o.z = fmaxf(o.z, 0.f);
            o.w = fmaxf(o.w, 0.f);
        }
        ((float4*)(h + (size_t)i * HID))[j] = o;
    }
}

// ---------------- GEMM2: g = (h1 @ W2) * dinv,  K=16 ----------------
__global__ __launch_bounds__(256) void k_gemm2(const float* __restrict__ h1,
                                               const float* __restrict__ W2,
                                               const float* __restrict__ dinv,
                                               float* __restrict__ g, int N) {
    __shared__ float w[HID * HID];
    if (threadIdx.x < HID * HID) w[threadIdx.x] = W2[threadIdx.x];
    __syncthreads();
    int i = blockIdx.x * 256 + threadIdx.x;
    if (i >= N) return;
    float hv[HID];
    const float4* hr = (const float4*)(h1 + (size_t)i * HID);
#pragma unroll
    for (int j = 0; j < 4; j++) {
        float4 v = hr[j];
        hv[j * 4 + 0] = v.x;
        hv[j * 4 + 1] = v.y;
        hv[j * 4 + 2] = v.z;
        hv[j * 4 + 3] = v.w;
    }
    float dv = dinv[i];
    float4* go = (float4*)(g + (size_t)i * HID);
#pragma unroll
    for (int n4 = 0; n4 < 4; n4++) {
        float4 o;
        float s0 = 0.f, s1 = 0.f, s2 = 0.f, s3 = 0.f;
#pragma unroll
        for (int k = 0; k < HID; k++) {
            s0 += hv[k] * w[k * HID + n4 * 4 + 0];
            s1 += hv[k] * w[k * HID + n4 * 4 + 1];
            s2 += hv[k] * w[k * HID + n4 * 4 + 2];
            s3 += hv[k] * w[k * HID + n4 * 4 + 3];
        }
        o.x = s0 * dv;
        o.y = s1 * dv;
        o.z = s2 * dv;
        o.w = s3 * dv;
        go[n4] = o;
    }
}

// ---------------- edge scoring ----------------
__global__ __launch_bounds__(256) void k_edge(const int* __restrict__ src,
                                              const int* __restrict__ dst,
                                              const float* __restrict__ h2,
                                              const float* __restrict__ Wf,
                                              const float* __restrict__ bf,
                                              float* __restrict__ pred, int E) {
    __shared__ float wf[33];
    if (threadIdx.x < 33) wf[threadIdx.x] = (threadIdx.x < 32) ? Wf[threadIdx.x] : bf[0];
    __syncthreads();
    int e = blockIdx.x * 256 + threadIdx.x;
    if (e >= E) return;
    int s = src[e], d = dst[e];
    const float4* hs = (const float4*)(h2 + (size_t)s * HID);
    const float4* hd = (const float4*)(h2 + (size_t)d * HID);
    float sum = wf[32];
#pragma unroll
    for (int j = 0; j < 4; j++) {
        float4 v = hs[j];
        sum += v.x * wf[j * 4 + 0] + v.y * wf[j * 4 + 1] + v.z * wf[j * 4 + 2] + v.w * wf[j * 4 + 3];
    }
#pragma unroll
    for (int j = 0; j < 4; j++) {
        float4 v = hd[j];
        sum += v.x * wf[16 + j * 4 + 0] + v.y * wf[16 + j * 4 + 1] + v.z * wf[16 + j * 4 + 2] +
               v.w * wf[16 + j * 4 + 3];
    }
    pred[e] = sum;
}

extern "C" void kernel_launch(void* const* d_in, const int* in_sizes, int n_in,
                              void* d_out, int out_size, void* d_ws, size_t ws_size,
                              hipStream_t stream) {
    const float* x  = (const float*)d_in[0];
    const int*   ei = (const int*)d_in[1];
    const float* W1 = (const float*)d_in[2];
    const float* b1 = (const float*)d_in[3];
    const float* W2 = (const float*)d_in[4];
    const float* b2 = (const float*)d_in[5];
    const float* Wf = (const float*)d_in[6];
    const float* bf = (const float*)d_in[7];
    float* pred = (float*)d_out;

    const int N = N_NODES, E = N_EDGES;
    const int* src = ei;
    const int* dst = ei + E;

    // workspace layout (bytes)
    char* w = (char*)d_ws;
    int*      gcount  = (int*)(w + 0x0);       // 25 KB (padded, stride 16)
    int*      bcursor = (int*)(w + 0x8000);    // 25 KB (padded, stride 16)
    int*      bbase   = (int*)(w + 0x10000);   // ~1.6 KB
    float*    dinv    = (float*)(w + 0x20000); // 400 KB
    int*      off     = (int*)(w + 0x90000);   // 400 KB + 4
    unsigned* ebuf    = (unsigned*)(w + 0x100000);  // 12.8 MB (bucketed, packed)
    int*      ebuf2   = (int*)(w + 0xD80000);       // 12.8 MB (exact CSR src)
    float*    g       = (float*)(w + 0x1A00000);    // 6.4 MB
    float*    h       = (float*)(w + 0x2040000);    // 6.4 MB -> total ~40 MB

    const int B = 256;
    int gE   = (E + B - 1) / B;       // 12500
    int gN   = (N + B - 1) / B;       // 391
    int gN2  = (N + 127) / 128;       // 782 (gemm1)
    int gN64 = (N * 64 + B - 1) / B;  // 25000 (wave per node)

    // coarse bucket partition + exact CSR via LDS counting sort
    hipMemsetAsync(gcount, 0, NB * CPAD * sizeof(int), stream);
    k_hist<<<512, B, 0, stream>>>(dst, gcount, E);
    k_scan<<<1, 512, 0, stream>>>(gcount, bbase, bcursor, E);
    k_part<<<NCHUNK, B, 0, stream>>>(src, dst, bcursor, ebuf, E);
    k_sort<<<NB, B, 0, stream>>>(ebuf, bbase, off, ebuf2, dinv, N, E);

    // conv1
    k_gemm1<<<gN2, B, 0, stream>>>(x, W1, dinv, g, N);
    k_gather<<<gN64, B, 0, stream>>>(g, off, ebuf2, dinv, b1, h, N, 1);

    // conv2
    k_gemm2<<<gN, B, 0, stream>>>(h, W2, dinv, g, N);
    k_gather<<<gN64, B, 0, stream>>>(g, off, ebuf2, dinv, b2, h, N, 0);

    // edge scoring
    k_edge<<<gE, B, 0, stream>>>(src, dst, h, Wf, bf, pred, E);
}

// Round 6
// 250.969 us; speedup vs baseline: 1.2595x; 1.2595x over previous
//
#include <hip/hip_runtime.h>

#define N_NODES 100000
#define N_EDGES 3200000
#define F_IN 128
#define HID 16

#define SHIFT 8
#define NPB 256                                 // nodes per bucket
#define NB ((N_NODES + NPB - 1) / NPB)          // 391 buckets
#define CHUNK 4096
#define NCHUNK ((N_EDGES + CHUNK - 1) / CHUNK)  // 782 chunks
#define MAXBE 12288                             // max edges per bucket
#define CPAD 16                                 // cursor stride (one 64B line per bucket)

// ---------------- bucket histogram ----------------
__global__ __launch_bounds__(256) void k_hist(const int* __restrict__ dst,
                                              int* __restrict__ gcount, int E) {
    __shared__ int cnt[NB];
    for (int b = threadIdx.x; b < NB; b += 256) cnt[b] = 0;
    __syncthreads();
    for (int e = blockIdx.x * 256 + threadIdx.x; e < E; e += gridDim.x * 256)
        atomicAdd(&cnt[dst[e] >> SHIFT], 1);
    __syncthreads();
    for (int b = threadIdx.x; b < NB; b += 256)
        if (cnt[b]) atomicAdd(&gcount[b * CPAD], cnt[b]);
}

// ---------------- scan buckets (1 block) ----------------
__global__ __launch_bounds__(512) void k_scan(const int* __restrict__ gcount,
                                              int* __restrict__ bbase,
                                              int* __restrict__ bcursor, int E) {
    __shared__ int s[512];
    int t = threadIdx.x;
    int v = (t < NB) ? gcount[t * CPAD] : 0;
    s[t] = v;
    __syncthreads();
#pragma unroll
    for (int o = 1; o < 512; o <<= 1) {
        int x = (t >= o) ? s[t - o] : 0;
        __syncthreads();
        s[t] += x;
        __syncthreads();
    }
    if (t < NB) {
        int ex = s[t] - v;
        bbase[t] = ex;
        bcursor[t * CPAD] = ex;
    }
    if (t == 0) bbase[NB] = E;
}

// ---------------- partition with LDS staging: coalesced bucket-run writes ----------------
__global__ __launch_bounds__(256) void k_part(const int* __restrict__ src,
                                              const int* __restrict__ dst,
                                              int* __restrict__ bcursor,
                                              unsigned* __restrict__ ebuf, int E) {
    __shared__ int lcnt[512];
    __shared__ int sc[512];
    __shared__ int lcur[512];
    __shared__ int dlt[512];
    __shared__ unsigned sbuf[CHUNK];         // 16 KB
    __shared__ unsigned short sbkt[CHUNK];   // 8 KB
    int t = threadIdx.x;
    lcnt[t] = 0;
    lcnt[t + 256] = 0;
    __syncthreads();
    int e0 = blockIdx.x * CHUNK;
    int e1 = min(e0 + CHUNK, E);
    int ne = e1 - e0;
    for (int e = t; e < ne; e += 256) atomicAdd(&lcnt[dst[e0 + e] >> SHIFT], 1);
    __syncthreads();
    // inclusive scan of 512 entries (two 256 segments in lockstep, then splice)
    sc[t] = lcnt[t];
    sc[t + 256] = lcnt[t + 256];
    __syncthreads();
#pragma unroll
    for (int o = 1; o < 256; o <<= 1) {
        int x = (t >= o) ? sc[t - o] : 0;
        int y = (t >= o) ? sc[256 + t - o] : 0;
        __syncthreads();
        sc[t] += x;
        sc[256 + t] += y;
        __syncthreads();
    }
    int tot1 = sc[255];
    __syncthreads();
    sc[256 + t] += tot1;
    __syncthreads();
    // exclusive local offsets; reserve global windows; dlt = gbase - lofs
    {
        int b1 = t, b2 = t + 256;
        int c1 = lcnt[b1], c2 = lcnt[b2];
        int o1 = sc[b1] - c1, o2 = sc[b2] - c2;
        lcur[b1] = o1;
        lcur[b2] = o2;
        if (b1 < NB && c1) dlt[b1] = atomicAdd(&bcursor[b1 * CPAD], c1) - o1;
        if (b2 < NB && c2) dlt[b2] = atomicAdd(&bcursor[b2 * CPAD], c2) - o2;
    }
    __syncthreads();
    // scatter into LDS, grouped by bucket
    for (int e = t; e < ne; e += 256) {
        int d = dst[e0 + e];
        int b = d >> SHIFT;
        int p = atomicAdd(&lcur[b], 1);
        sbuf[p] = ((unsigned)src[e0 + e] << SHIFT) | (unsigned)(d & (NPB - 1));
        sbkt[p] = (unsigned short)b;
    }
    __syncthreads();
    // coalesced write-out: consecutive k -> consecutive global positions within runs
    for (int k = t; k < ne; k += 256) {
        ebuf[k + dlt[sbkt[k]]] = sbuf[k];
    }
}

// ---------------- per-bucket LDS counting-sort -> exact CSR (+dinv) ----------------
__global__ __launch_bounds__(256) void k_sort(const unsigned* __restrict__ ebuf,
                                              const int* __restrict__ bbase,
                                              int* __restrict__ off,
                                              int* __restrict__ ebuf2,
                                              float* __restrict__ dinv, int N, int E) {
    __shared__ int hist[NPB];
    __shared__ int sc[NPB];
    __shared__ int cur[NPB];
    __shared__ int sbuf[MAXBE];  // 48 KB
    int t = threadIdx.x;
    int b = blockIdx.x;
    int e0 = bbase[b], e1 = bbase[b + 1];
    int ne = e1 - e0;
    hist[t] = 0;
    __syncthreads();
    for (int e = t; e < ne; e += 256) atomicAdd(&hist[ebuf[e0 + e] & (NPB - 1)], 1);
    __syncthreads();
    int v = hist[t];
    sc[t] = v;
    __syncthreads();
#pragma unroll
    for (int o = 1; o < 256; o <<= 1) {
        int x = (t >= o) ? sc[t - o] : 0;
        __syncthreads();
        sc[t] += x;
        __syncthreads();
    }
    int ex = sc[t] - v;  // exclusive prefix within bucket
    cur[t] = ex;
    int i = (b << SHIFT) + t;
    if (i < N) {
        off[i] = e0 + ex;
        dinv[i] = rsqrtf((float)(v + 1));  // +1 self-loop
    }
    if (b == NB - 1 && t == 0) off[N] = E;
    __syncthreads();
    for (int e = t; e < ne; e += 256) {
        unsigned u = ebuf[e0 + e];
        int p = atomicAdd(&cur[u & (NPB - 1)], 1);
        sbuf[p] = (int)(u >> SHIFT);
    }
    __syncthreads();
    for (int e = t; e < ne; e += 256) ebuf2[e0 + e] = sbuf[e];  // coalesced
}

// ---------------- GEMM1: g = (x @ W1) * dinv,  K=128, lane-pair per row ----------------
__global__ __launch_bounds__(256) void k_gemm1(const float* __restrict__ x,
                                               const float* __restrict__ W1,
                                               const float* __restrict__ dinv,
                                               float* __restrict__ g, int N) {
    __shared__ float w[F_IN * HID];
    for (int t = threadIdx.x; t < F_IN * HID; t += 256) w[t] = W1[t];
    __syncthreads();
    int t = threadIdx.x;
    int half = t & 1;
    int i = blockIdx.x * 128 + (t >> 1);
    float acc[HID];
#pragma unroll
    for (int n = 0; n < HID; n++) acc[n] = 0.f;
    if (i < N) {
        const float4* xr = (const float4*)(x + (size_t)i * F_IN + half * (F_IN / 2));
#pragma unroll 4
        for (int k4 = 0; k4 < F_IN / 8; k4++) {
            float4 xv = xr[k4];
            int k = half * (F_IN / 2) + k4 * 4;
#pragma unroll
            for (int n = 0; n < HID; n++) {
                acc[n] += xv.x * w[(k + 0) * HID + n] + xv.y * w[(k + 1) * HID + n] +
                          xv.z * w[(k + 2) * HID + n] + xv.w * w[(k + 3) * HID + n];
            }
        }
    }
#pragma unroll
    for (int n = 0; n < HID; n++) acc[n] += __shfl_xor(acc[n], 1);
    if (half == 0 && i < N) {
        float dv = dinv[i];
        float4* go = (float4*)(g + (size_t)i * HID);
#pragma unroll
        for (int n4 = 0; n4 < 4; n4++) {
            float4 o;
            o.x = acc[n4 * 4 + 0] * dv;
            o.y = acc[n4 * 4 + 1] * dv;
            o.z = acc[n4 * 4 + 2] * dv;
            o.w = acc[n4 * 4 + 3] * dv;
            go[n4] = o;
        }
    }
}

// ---------------- gather-sum + finish: wave per node ----------------
__global__ __launch_bounds__(256) void k_gather(const float* __restrict__ g,
                                                const int* __restrict__ off,
                                                const int* __restrict__ ebuf,
                                                const float* __restrict__ dinv,
                                                const float* __restrict__ bias,
                                                float* __restrict__ h, int N, int do_relu) {
    int i = (blockIdx.x * 256 + threadIdx.x) >> 6;  // node = global wave id
    int lane = threadIdx.x & 63;
    if (i >= N) return;
    int e0 = off[i], e1 = off[i + 1];
    int j = lane & 3;
    float4 a = make_float4(0.f, 0.f, 0.f, 0.f);
    for (int e = e0 + (lane >> 2); e < e1; e += 16) {
        int s = ebuf[e];
        float4 v = ((const float4*)(g + (size_t)s * HID))[j];
        a.x += v.x;
        a.y += v.y;
        a.z += v.z;
        a.w += v.w;
    }
#pragma unroll
    for (int m = 4; m <= 32; m <<= 1) {
        a.x += __shfl_xor(a.x, m);
        a.y += __shfl_xor(a.y, m);
        a.z += __shfl_xor(a.z, m);
        a.w += __shfl_xor(a.w, m);
    }
    if (lane < 4) {
        float4 self = ((const float4*)(g + (size_t)i * HID))[j];
        float4 bb = ((const float4*)bias)[j];
        float dv = dinv[i];
        float4 o;
        o.x = dv * (a.x + self.x) + bb.x;
        o.y = dv * (a.y + self.y) + bb.y;
        o.z = dv * (a.z + self.z) + bb.z;
        o.w = dv * (a.w + self.w) + bb.w;
        if (do_relu) {
            o.x = fmaxf(o.x, 0.f);
            o.y = fmaxf(o.y, 0.f);
            o.z = fmaxf(o.z, 0.f);
            o.w = fmaxf(o.w, 0.f);
        }
        ((float4*)(h + (size_t)i * HID))[j] = o;
    }
}

// ---------------- GEMM2: g = (h1 @ W2) * dinv,  K=16 ----------------
__global__ __launch_bounds__(256) void k_gemm2(const float* __restrict__ h1,
                                               const float* __restrict__ W2,
                                               const float* __restrict__ dinv,
                                               float* __restrict__ g, int N) {
    __shared__ float w[HID * HID];
    if (threadIdx.x < HID * HID) w[threadIdx.x] = W2[threadIdx.x];
    __syncthreads();
    int i = blockIdx.x * 256 + threadIdx.x;
    if (i >= N) return;
    float hv[HID];
    const float4* hr = (const float4*)(h1 + (size_t)i * HID);
#pragma unroll
    for (int j = 0; j < 4; j++) {
        float4 v = hr[j];
        hv[j * 4 + 0] = v.x;
        hv[j * 4 + 1] = v.y;
        hv[j * 4 + 2] = v.z;
        hv[j * 4 + 3] = v.w;
    }
    float dv = dinv[i];
    float4* go = (float4*)(g + (size_t)i * HID);
#pragma unroll
    for (int n4 = 0; n4 < 4; n4++) {
        float4 o;
        float s0 = 0.f, s1 = 0.f, s2 = 0.f, s3 = 0.f;
#pragma unroll
        for (int k = 0; k < HID; k++) {
            s0 += hv[k] * w[k * HID + n4 * 4 + 0];
            s1 += hv[k] * w[k * HID + n4 * 4 + 1];
            s2 += hv[k] * w[k * HID + n4 * 4 + 2];
            s3 += hv[k] * w[k * HID + n4 * 4 + 3];
        }
        o.x = s0 * dv;
        o.y = s1 * dv;
        o.z = s2 * dv;
        o.w = s3 * dv;
        go[n4] = o;
    }
}

// ---------------- node dots: nd[i] = (dot(h2,Wf_lo), dot(h2,Wf_hi)+bf) ----------------
__global__ __launch_bounds__(256) void k_nodedot(const float* __restrict__ h2,
                                                 const float* __restrict__ Wf,
                                                 const float* __restrict__ bf,
                                                 float2* __restrict__ nd, int N) {
    __shared__ float wf[33];
    if (threadIdx.x < 33) wf[threadIdx.x] = (threadIdx.x < 32) ? Wf[threadIdx.x] : bf[0];
    __syncthreads();
    int i = blockIdx.x * 256 + threadIdx.x;
    if (i >= N) return;
    const float4* hr = (const float4*)(h2 + (size_t)i * HID);
    float ps = 0.f, pd = wf[32];
#pragma unroll
    for (int j = 0; j < 4; j++) {
        float4 v = hr[j];
        ps += v.x * wf[j * 4 + 0] + v.y * wf[j * 4 + 1] + v.z * wf[j * 4 + 2] + v.w * wf[j * 4 + 3];
        pd += v.x * wf[16 + j * 4 + 0] + v.y * wf[16 + j * 4 + 1] + v.z * wf[16 + j * 4 + 2] +
              v.w * wf[16 + j * 4 + 3];
    }
    nd[i] = make_float2(ps, pd);
}

// ---------------- edge scoring: 8 B random reads from L2-resident nd ----------------
__global__ __launch_bounds__(256) void k_edge2(const int* __restrict__ src,
                                               const int* __restrict__ dst,
                                               const float2* __restrict__ nd,
                                               float* __restrict__ pred, int E) {
    int e = blockIdx.x * 256 + threadIdx.x;
    if (e >= E) return;
    pred[e] = nd[src[e]].x + nd[dst[e]].y;
}

extern "C" void kernel_launch(void* const* d_in, const int* in_sizes, int n_in,
                              void* d_out, int out_size, void* d_ws, size_t ws_size,
                              hipStream_t stream) {
    const float* x  = (const float*)d_in[0];
    const int*   ei = (const int*)d_in[1];
    const float* W1 = (const float*)d_in[2];
    const float* b1 = (const float*)d_in[3];
    const float* W2 = (const float*)d_in[4];
    const float* b2 = (const float*)d_in[5];
    const float* Wf = (const float*)d_in[6];
    const float* bf = (const float*)d_in[7];
    float* pred = (float*)d_out;

    const int N = N_NODES, E = N_EDGES;
    const int* src = ei;
    const int* dst = ei + E;

    // workspace layout (bytes); g/h alias dead ebuf space after k_sort
    char* w = (char*)d_ws;
    int*      gcount  = (int*)(w + 0x0);        // 25 KB (stride CPAD)
    int*      bcursor = (int*)(w + 0x8000);     // 25 KB (stride CPAD)
    int*      bbase   = (int*)(w + 0x10000);    // ~1.6 KB
    float*    dinv    = (float*)(w + 0x20000);  // 400 KB
    int*      off     = (int*)(w + 0x90000);    // 400 KB + 4
    float2*   nd      = (float2*)(w + 0x100000);   // 800 KB
    unsigned* ebuf    = (unsigned*)(w + 0x200000); // 12.8 MB (dead after k_sort)
    float*    g       = (float*)(w + 0x200000);    // 6.4 MB (aliases ebuf lo)
    float*    h       = (float*)(w + 0x81A800);    // 6.4 MB (aliases ebuf hi)
    int*      ebuf2   = (int*)(w + 0xEC0000);      // 12.8 MB -> total ~28.3 MB

    const int B = 256;
    int gE   = (E + B - 1) / B;       // 12500
    int gN   = (N + B - 1) / B;       // 391
    int gN2  = (N + 127) / 128;       // 782 (gemm1)
    int gN64 = (N * 64 + B - 1) / B;  // 25000 (wave per node)

    // coarse bucket partition + exact CSR via LDS counting sort
    hipMemsetAsync(gcount, 0, NB * CPAD * sizeof(int), stream);
    k_hist<<<512, B, 0, stream>>>(dst, gcount, E);
    k_scan<<<1, 512, 0, stream>>>(gcount, bbase, bcursor, E);
    k_part<<<NCHUNK, B, 0, stream>>>(src, dst, bcursor, ebuf, E);
    k_sort<<<NB, B, 0, stream>>>(ebuf, bbase, off, ebuf2, dinv, N, E);

    // conv1
    k_gemm1<<<gN2, B, 0, stream>>>(x, W1, dinv, g, N);
    k_gather<<<gN64, B, 0, stream>>>(g, off, ebuf2, dinv, b1, h, N, 1);

    // conv2
    k_gemm2<<<gN, B, 0, stream>>>(h, W2, dinv, g, N);
    k_gather<<<gN64, B, 0, stream>>>(g, off, ebuf2, dinv, b2, h, N, 0);

    // edge scoring (decomposed: per-node dots then 8B random reads)
    k_nodedot<<<gN, B, 0, stream>>>(h, Wf, bf, nd, N);
    k_edge2<<<gE, B, 0, stream>>>(src, dst, nd, pred, E);
}